// Round 1
// 1311.130 us; speedup vs baseline: 3.0810x; 3.0810x over previous
//
#include <hip/hip_runtime.h>
#include <hip/hip_bf16.h>

using bf16 = __hip_bfloat16;
typedef __attribute__((ext_vector_type(8))) short bfrag;   // 8 x bf16 (4 VGPR)
typedef __attribute__((ext_vector_type(4))) float ffrag;   // 4 x f32 acc

__device__ __forceinline__ float b2f(bf16 v) { return __bfloat162float(v); }
__device__ __forceinline__ float ldin(const void* p, int i, int isbf) {
    return isbf ? b2f(((const bf16*)p)[i]) : ((const float*)p)[i];
}
// exact-ish two-term bf16 split: v ~= hi + lo, |err| <= 2^-17 |v|
__device__ __forceinline__ void split2(float v, unsigned short& h, unsigned short& l) {
    bf16 hb = __float2bfloat16(v);
    h = __bfloat16_as_ushort(hb);
    l = __bfloat16_as_ushort(__float2bfloat16(v - __bfloat162float(hb)));
}

// ---------------------------------------------------------------------------
// dtype detector (unchanged)
// ---------------------------------------------------------------------------
__global__ void detect_kernel(const unsigned* __restrict__ x, int* __restrict__ flag)
{
    int tid = threadIdx.x;
    int cnt = 0;
    for (int i = tid; i < 256; i += 64) {
        unsigned e = (x[i] >> 7) & 0xFFu;
        cnt += (e >= 110u && e <= 135u) ? 1 : 0;
    }
#pragma unroll
    for (int off = 32; off > 0; off >>= 1) cnt += __shfl_down(cnt, off, 64);
    if (tid == 0) *flag = (cnt >= 128) ? 1 : 0;
}

// ---------------------------------------------------------------------------
// zero the BN accumulator area (896 floats)
// ---------------------------------------------------------------------------
__global__ void zero_accum_kernel(float* __restrict__ a)
{
    for (int i = threadIdx.x; i < 896; i += 256) a[i] = 0.f;
}

// ---------------------------------------------------------------------------
// weight pre-split: w[COUT][CIN][3][3] (flag dtype) -> fragment-major bf16
// hi/lo tensors. Element order: fb = (tap*NCH + ch)*NCOG + cg, then within the
// 512-elem fragment block: lane l (co = cg*16 + (l&15), ci-oct = l>>4), j.
// One dwordx4 per lane at load time.
// ---------------------------------------------------------------------------
template<int CIN, int COUT>
__global__ __launch_bounds__(256)
void wsplit_kernel(const void* __restrict__ w, unsigned short* __restrict__ whi,
                   unsigned short* __restrict__ wlo, const int* __restrict__ flagp)
{
    constexpr int NCH = CIN / 32, NCOG = COUT / 16;
    constexpr int total = 9 * NCH * NCOG * 512;
    int isbf = *flagp;
    int o = blockIdx.x * 256 + threadIdx.x;
    if (o >= total) return;
    int j = o & 7;
    int l = (o >> 3) & 63;
    int fb = o >> 9;
    int cg = fb % NCOG;
    int t2 = fb / NCOG;
    int ch = t2 % NCH;
    int tap = t2 / NCH;
    int co = cg * 16 + (l & 15);
    int ci = ch * 32 + (l >> 4) * 8 + j;
    float v = ldin(w, (co * CIN + ci) * 9 + tap, isbf);
    unsigned short h, lo2;
    split2(v, h, lo2);
    whi[o] = h;
    wlo[o] = lo2;
}

// ---------------------------------------------------------------------------
// MFMA implicit-GEMM 3x3 conv, pad=1, NHWC f32 output u = conv + bias.
// Tile: TH rows x W cols (=256 px) x 64 couts; 4 waves, each 64px x 64co.
// Input staged per 32-ci chunk in LDS as bf16 hi/lo, layout [ci-oct][pix][8].
// Weights read as pre-split global fragments (L2-resident).
//   EXTIN: input NCHW flag-dtype (else NHWC f32 intermediate)
//   SMAP : multiply input by (dilate3(imap)-imap), computed inline
//   EPI  : out = dep + beta*(conv+bias)
//   BNIN : apply BN(accum,g,be)+ReLU to the f32 NHWC input during staging
// ---------------------------------------------------------------------------
template<int CIN, int COUT, int H, int W, int TH,
         bool EXTIN, bool SMAP, bool EPI, bool BNIN>
__global__ __launch_bounds__(256, 2)
void conv3_mfma(const void* __restrict__ in,
                const unsigned short* __restrict__ whi,
                const unsigned short* __restrict__ wlo,
                const void* __restrict__ bias,
                const float* __restrict__ imapF,
                const float* __restrict__ dep,
                const void* __restrict__ betap,
                const float* __restrict__ accum,
                const void* __restrict__ bng, const void* __restrict__ bnbe,
                float* __restrict__ out, const int* __restrict__ flagp)
{
    constexpr int NCH  = CIN / 32;
    constexpr int NCOG = COUT / 16;
    constexpr int W2   = W + 2;
    constexpr int NP   = (TH + 2) * W2;   // halo pixels
    constexpr int NPs  = NP + 1;          // padded plane stride (bank spread)
    constexpr int NE   = 4 * NP;

    __shared__ int4 s_hi[4 * NPs];
    __shared__ int4 s_lo[4 * NPs];
    __shared__ float s_ss[128];                 // BNIN: per-ch scale/shift
    __shared__ float s_sm[SMAP ? NP : 1];       // SMAP: per-pixel scale

    const int isbf = *flagp;
    const int tid  = threadIdx.x;
    const int r0   = blockIdx.x * TH;           // global row in [0, B*H)
    const int bimg = r0 / H;
    const int y0im = bimg * H;
    const int coB  = blockIdx.y;

    if (BNIN) {
        if (tid < CIN) {
            const float n = (float)(16 * H * W);
            float S = accum[tid], S2 = accum[CIN + tid];
            float m = S / n;
            float var = fmaxf(S2 / n - m * m, 0.f);
            float scv = ldin(bng, tid, isbf) * rsqrtf(var + 1e-5f);
            s_ss[2 * tid]     = scv;
            s_ss[2 * tid + 1] = ldin(bnbe, tid, isbf) - m * scv;
        }
    }
    if (SMAP) {
        const float* ip = imapF + ((size_t)bimg << 14);   // H=W=128 only
        for (int i = tid; i < NP; i += 256) {
            int rr = i / W2, cc = i - rr * W2;
            int gy = r0 - 1 + rr, gx = cc - 1;
            float sm = 0.f;
            if (gy >= y0im && gy < y0im + H && (unsigned)gx < (unsigned)W) {
                int y = gy - y0im;
                float ctr = ip[(y << 7) + gx];
                float mx = ctr;
#pragma unroll
                for (int dy = -1; dy <= 1; dy++) {
                    int yy = y + dy;
                    if ((unsigned)yy < 128u) {
#pragma unroll
                        for (int dx = -1; dx <= 1; dx++) {
                            int xx = gx + dx;
                            if ((unsigned)xx < 128u) mx = fmaxf(mx, ip[(yy << 7) + xx]);
                        }
                    }
                }
                sm = mx - ctr;
            }
            s_sm[i] = sm;
        }
    }

    const int lane = tid & 63;
    const int wv = tid >> 6;
    const int lx = lane & 15;
    const int gq = lane >> 4;

    ffrag acc[4][4];
#pragma unroll
    for (int mf = 0; mf < 4; mf++)
#pragma unroll
        for (int nf = 0; nf < 4; nf++) acc[mf][nf] = ffrag{0.f, 0.f, 0.f, 0.f};

    for (int ch = 0; ch < NCH; ch++) {
        const int c0 = ch * 32;
        __syncthreads();
        // ---------------- stage halo tile (32 channels) ----------------
        for (int e = tid; e < NE; e += 256) {
            int gg, pixin;
            if (EXTIN) { gg = e / NP; pixin = e - gg * NP; }   // pix-contig lanes
            else       { gg = e & 3;  pixin = e >> 2; }        // 32B/lane NHWC
            int rr = pixin / W2;
            int cc2 = pixin - rr * W2;
            int gy = r0 - 1 + rr;
            int gx = cc2 - 1;
            float v[8];
            bool ok = (gy >= y0im) && (gy < y0im + H) && ((unsigned)gx < (unsigned)W);
            if (ok) {
                if (EXTIN) {
                    int y = gy - y0im;
                    float sm = SMAP ? s_sm[pixin] : 1.f;
#pragma unroll
                    for (int j = 0; j < 8; j++) {
                        int gi = ((bimg * CIN + c0 + 8 * gg + j) * H + y) * W + gx;
                        v[j] = ldin(in, gi, isbf) * sm;
                    }
                } else {
                    const float* up = (const float*)in +
                        ((size_t)gy * W + gx) * CIN + c0 + 8 * gg;
                    float4 q0 = *(const float4*)up;
                    float4 q1 = *(const float4*)(up + 4);
                    v[0] = q0.x; v[1] = q0.y; v[2] = q0.z; v[3] = q0.w;
                    v[4] = q1.x; v[5] = q1.y; v[6] = q1.z; v[7] = q1.w;
                    if (BNIN) {
#pragma unroll
                        for (int j = 0; j < 8; j++) {
                            int chn = c0 + 8 * gg + j;
                            v[j] = fmaxf(fmaf(v[j], s_ss[2 * chn], s_ss[2 * chn + 1]), 0.f);
                        }
                    }
                }
            } else {
#pragma unroll
                for (int j = 0; j < 8; j++) v[j] = 0.f;
            }
            unsigned hp[4], lp[4];
#pragma unroll
            for (int j2 = 0; j2 < 4; j2++) {
                unsigned short h0, l0, h1, l1;
                split2(v[2 * j2], h0, l0);
                split2(v[2 * j2 + 1], h1, l1);
                hp[j2] = (unsigned)h0 | ((unsigned)h1 << 16);
                lp[j2] = (unsigned)l0 | ((unsigned)l1 << 16);
            }
            s_hi[gg * NPs + pixin] = make_int4(hp[0], hp[1], hp[2], hp[3]);
            s_lo[gg * NPs + pixin] = make_int4(lp[0], lp[1], lp[2], lp[3]);
        }
        __syncthreads();
        // ---------------- compute: 9 taps, shift-GEMM ----------------
#pragma unroll
        for (int tap = 0; tap < 9; tap++) {
            const int ky = tap / 3, kx = tap % 3;
            bfrag ah[4], al[4];
#pragma unroll
            for (int mf = 0; mf < 4; mf++) {
                int p = 64 * wv + 16 * mf;                 // tile-local pixel base
                int rI = p / W + ky;
                int cI = (p & (W - 1)) + kx + lx;
                int pix = rI * W2 + cI;
                ah[mf] = ((const bfrag*)s_hi)[gq * NPs + pix];
                al[mf] = ((const bfrag*)s_lo)[gq * NPs + pix];
            }
            bfrag bh[4];
#pragma unroll
            for (int nf = 0; nf < 4; nf++) {
                int fb = (tap * NCH + ch) * NCOG + coB * 4 + nf;
                bh[nf] = ((const bfrag*)(whi + (size_t)fb * 512))[lane];
            }
#pragma unroll
            for (int nf = 0; nf < 4; nf++)
#pragma unroll
                for (int mf = 0; mf < 4; mf++) {
                    acc[mf][nf] = __builtin_amdgcn_mfma_f32_16x16x32_bf16(
                        ah[mf], bh[nf], acc[mf][nf], 0, 0, 0);
                    acc[mf][nf] = __builtin_amdgcn_mfma_f32_16x16x32_bf16(
                        al[mf], bh[nf], acc[mf][nf], 0, 0, 0);
                }
            if (!isbf) {   // f32 inputs: third term a_hi * w_lo
                bfrag bl[4];
#pragma unroll
                for (int nf = 0; nf < 4; nf++) {
                    int fb = (tap * NCH + ch) * NCOG + coB * 4 + nf;
                    bl[nf] = ((const bfrag*)(wlo + (size_t)fb * 512))[lane];
                }
#pragma unroll
                for (int nf = 0; nf < 4; nf++)
#pragma unroll
                    for (int mf = 0; mf < 4; mf++)
                        acc[mf][nf] = __builtin_amdgcn_mfma_f32_16x16x32_bf16(
                            ah[mf], bl[nf], acc[mf][nf], 0, 0, 0);
            }
        }
    }
    // ---------------- epilogue: NHWC f32 store ----------------
    const float beta = EPI ? ldin(betap, 0, isbf) : 0.f;
#pragma unroll
    for (int nf = 0; nf < 4; nf++) {
        int co = coB * 64 + nf * 16 + lx;
        float bi = ldin(bias, co, isbf);
#pragma unroll
        for (int mf = 0; mf < 4; mf++) {
#pragma unroll
            for (int r2 = 0; r2 < 4; r2++) {
                int p = 64 * wv + 16 * mf + gq * 4 + r2;
                int grow = r0 + p / W;
                int gcol = p & (W - 1);
                size_t oi = ((size_t)grow * W + gcol) * COUT + co;
                float vo = acc[mf][nf][r2] + bi;
                if (EPI) vo = dep[oi] + beta * vo;
                out[oi] = vo;
            }
        }
    }
}

// ---------------------------------------------------------------------------
// BN stats over NHWC f32 u: per-channel sum / sumsq -> atomicAdd accum[2][C]
// ---------------------------------------------------------------------------
template<int C>
__global__ __launch_bounds__(256)
void stats_nhwc_kernel(const float* __restrict__ u, float* __restrict__ accum, int npix)
{
    constexpr int P = 256 / C;
    int tid = threadIdx.x;
    int c = tid & (C - 1);
    int ps = tid / C;
    float s = 0.f, s2 = 0.f;
    for (int p = blockIdx.x * P + ps; p < npix; p += gridDim.x * P) {
        float v = u[(size_t)p * C + c];
        s += v;
        s2 = fmaf(v, v, s2);
    }
    if (P > 1) {
        __shared__ float r1[256], r2[256];
        r1[tid] = s; r2[tid] = s2;
        __syncthreads();
        if (tid < C) {
#pragma unroll
            for (int q = 1; q < P; q++) { s += r1[tid + q * C]; s2 += r2[tid + q * C]; }
        }
    }
    if (tid < C) {
        atomicAdd(&accum[c], s);
        atomicAdd(&accum[C + c], s2);
    }
}

// ---------------------------------------------------------------------------
// pixel_shuffle(2) + BN + ReLU, NHWC: u1 [B*64*64][256] -> dep [B*128*128][64]
// ---------------------------------------------------------------------------
__global__ __launch_bounds__(256)
void shuffle_bn_nhwc_kernel(const float* __restrict__ u, const float* __restrict__ accum,
                            const void* __restrict__ g, const void* __restrict__ be,
                            float* __restrict__ dep, const int* __restrict__ flagp)
{
    int isbf = *flagp;
    int tid = threadIdx.x;
    int c = tid & 63, ps = tid >> 6;
    float sc[4], sh[4];
#pragma unroll
    for (int q = 0; q < 4; q++) {
        int chn = 4 * c + q;
        float S = accum[chn], S2 = accum[256 + chn];
        const float n = 65536.f;
        float m = S / n;
        float var = fmaxf(S2 / n - m * m, 0.f);
        sc[q] = ldin(g, chn, isbf) * rsqrtf(var + 1e-5f);
        sh[q] = ldin(be, chn, isbf) - m * sc[q];
    }
    for (int sp = blockIdx.x * 4 + ps; sp < 65536; sp += gridDim.x * 4) {
        float4 q4 = *(const float4*)(u + (size_t)sp * 256 + 4 * c);
        float vals[4] = {q4.x, q4.y, q4.z, q4.w};
        int b = sp >> 12, rem = sp & 4095, y2 = rem >> 6, x2 = rem & 63;
#pragma unroll
        for (int dy = 0; dy < 2; dy++)
#pragma unroll
            for (int dx = 0; dx < 2; dx++) {
                int q = 2 * dy + dx;
                float v = fmaxf(fmaf(vals[q], sc[q], sh[q]), 0.f);
                size_t op = (size_t)(b * 128 + 2 * y2 + dy) * 128 + (2 * x2 + dx);
                dep[op * 64 + c] = v;
            }
    }
}

// ---------------------------------------------------------------------------
// bilinear up2 (align_corners) + sigmoid (unchanged math)
// ---------------------------------------------------------------------------
__global__ __launch_bounds__(256)
void imap_kernel(const void* __restrict__ im, float* __restrict__ imap,
                 const int* __restrict__ flagp)
{
    int isbf = *flagp;
    int idx = blockIdx.x * 256 + threadIdx.x;
    int x = idx & 127, y = (idx >> 7) & 127, b = idx >> 14;
    const float s = (float)(63.0 / 127.0);
    float yy = y * s, xx = x * s;
    int y0 = (int)yy, x0 = (int)xx;
    float wy = yy - y0, wx = xx - x0;
    int y1 = min(y0 + 1, 63), x1 = min(x0 + 1, 63);
    int base = b << 12;
    float v00 = ldin(im, base + (y0 << 6) + x0, isbf);
    float v01 = ldin(im, base + (y0 << 6) + x1, isbf);
    float v10 = ldin(im, base + (y1 << 6) + x0, isbf);
    float v11 = ldin(im, base + (y1 << 6) + x1, isbf);
    float r0 = v00 * (1.f - wy) + v10 * wy;
    float r1 = v01 * (1.f - wy) + v11 * wy;
    float v = r0 * (1.f - wx) + r1 * wx;
    imap[idx] = 1.f / (1.f + expf(-v));
}

// ---------------------------------------------------------------------------
// final BN+ReLU + NHWC->NCHW transpose: u3 -> r3 f32 (for conv7x7) + d_out
// ---------------------------------------------------------------------------
__global__ __launch_bounds__(256)
void bn_transpose_out_kernel(const float* __restrict__ u, const float* __restrict__ accum,
                             const void* __restrict__ g, const void* __restrict__ be,
                             float* __restrict__ r3, void* __restrict__ dout,
                             const int* __restrict__ flagp)
{
    int isbf = *flagp;
    int tid = threadIdx.x;
    int c = tid & 63, ps = tid >> 6;
    float S = accum[c], S2 = accum[64 + c];
    const float n = 262144.f;
    float m = S / n;
    float var = fmaxf(S2 / n - m * m, 0.f);
    float sc = ldin(g, c, isbf) * rsqrtf(var + 1e-5f);
    float sh = ldin(be, c, isbf) - m * sc;
    __shared__ float s[64][65];
    int pix0 = blockIdx.x * 64;
#pragma unroll
    for (int ii = 0; ii < 16; ii++) {
        int p = ps + 4 * ii;
        float v = u[(size_t)(pix0 + p) * 64 + c];
        s[p][c] = fmaxf(fmaf(v, sc, sh), 0.f);
    }
    __syncthreads();
    int x = c;
    int row = pix0 >> 7, col0 = pix0 & 127;
    int b = row >> 7, y = row & 127;
#pragma unroll
    for (int jj = 0; jj < 16; jj++) {
        int cc = ps + 4 * jj;
        float v = s[x][cc];
        size_t oi = (((size_t)(b * 64 + cc)) << 14) + (y << 7) + col0 + x;
        r3[oi] = v;
        if (isbf) ((bf16*)dout)[oi] = __float2bfloat16(v);
        else      ((float*)dout)[oi] = v;
    }
}

// ---------------------------------------------------------------------------
// 7x7 conv, 64 -> 1, pad=3 (unchanged; reads r3 NCHW f32)
// ---------------------------------------------------------------------------
__global__ __launch_bounds__(256)
void conv7x7_kernel(const float* __restrict__ r, const void* __restrict__ w,
                    const void* __restrict__ bias, void* __restrict__ outv,
                    const int* __restrict__ flagp)
{
    __shared__ float s_in[4][70][22];
    const int isbf = *flagp;
    int tid = threadIdx.x;
    int tx = tid & 15, ty = tid >> 4;
    int x0 = blockIdx.x * 16, y0 = blockIdx.y * 64, b = blockIdx.z;
    float acc[4] = {0.f, 0.f, 0.f, 0.f};

    for (int c0 = 0; c0 < 64; c0 += 4) {
        __syncthreads();
        for (int i = tid; i < 4 * 70 * 22; i += 256) {
            int ci = i / (70 * 22);
            int rem = i - ci * (70 * 22);
            int rr = rem / 22, cc = rem - rr * 22;
            int gy = y0 + rr - 3, gx = x0 + cc - 3;
            float v = 0.f;
            if ((unsigned)gy < 128u && (unsigned)gx < 128u)
                v = r[((b * 64 + c0 + ci) << 14) + (gy << 7) + gx];
            s_in[ci][rr][cc] = v;
        }
        __syncthreads();
        for (int ci = 0; ci < 4; ci++) {
            float wr[49];
#pragma unroll
            for (int k = 0; k < 49; k++) wr[k] = ldin(w, (c0 + ci) * 49 + k, isbf);
#pragma unroll
            for (int rr = 0; rr < 10; rr++) {
                float row[7];
#pragma unroll
                for (int c = 0; c < 7; c++) row[c] = s_in[ci][4 * ty + rr][tx + c];
#pragma unroll
                for (int oy = 0; oy < 4; oy++) {
                    int ky = rr - oy;
                    if (ky >= 0 && ky <= 6) {
#pragma unroll
                        for (int kx = 0; kx < 7; kx++)
                            acc[oy] = fmaf(row[kx], wr[ky * 7 + kx], acc[oy]);
                    }
                }
            }
        }
    }
    float bi = ldin(bias, 0, isbf);
#pragma unroll
    for (int oy = 0; oy < 4; oy++) {
        int y = y0 + 4 * ty + oy;
        int oidx = 16777216 + (b << 14) + (y << 7) + x0 + tx;
        float v = acc[oy] + bi;
        if (isbf) ((bf16*)outv)[oidx] = __float2bfloat16(v);
        else      ((float*)outv)[oidx] = v;
    }
}

// ---------------------------------------------------------------------------
// ws layout (unchanged footprint, 134,221,828 B):
//   [0, 64MB)            W0  (u1 / t / u_d2 / r3-NCHW)      NHWC f32
//   [64MB, 128MB)        W1  (dep / u_d1 / u_d3)            NHWC f32
//   [134217728, +3.5KB)  accum: a0[512] a1[128] a2[128] a3[128]
//   [134221824, +4B)     flag
// d_out head (dead until bn_transpose_out) holds scratch:
//   split weights (1.77MB) + imapF (1MB)  -- all consumed before final writes
// ---------------------------------------------------------------------------
extern "C" void kernel_launch(void* const* d_in, const int* in_sizes, int n_in,
                              void* d_out, int out_size, void* d_ws, size_t ws_size,
                              hipStream_t stream)
{
    (void)in_sizes; (void)n_in; (void)out_size; (void)ws_size;

    const void* cur_x   = d_in[0];
    const void* dep_x   = d_in[1];
    const void* in_map  = d_in[2];
    const void* up_w    = d_in[3];
    const void* up_b    = d_in[4];
    const void* up_g    = d_in[5];
    const void* up_be   = d_in[6];
    const void* conv2_w = d_in[7];
    const void* conv2_b = d_in[8];
    const void* beta    = d_in[9];
    const void* d1_w = d_in[10];
    const void* d1_b = d_in[11];
    const void* d1_g = d_in[12];
    const void* d1_be = d_in[13];
    const void* d2_w = d_in[14];
    const void* d2_b = d_in[15];
    const void* d2_g = d_in[16];
    const void* d2_be = d_in[17];
    const void* d3_w = d_in[18];
    const void* d3_b = d_in[19];
    const void* d3_g = d_in[20];
    const void* d3_be = d_in[21];
    const void* out_w = d_in[22];
    const void* out_b = d_in[23];

    char* ws = (char*)d_ws;
    float* W0    = (float*)ws;
    float* W1    = (float*)(ws + 67108864);
    float* accum = (float*)(ws + 134217728);
    int*   flag  = (int*)(ws + 134221824);
    float* a0 = accum;
    float* a1 = accum + 512;
    float* a2 = accum + 640;
    float* a3 = accum + 768;

    char* sc = (char*)d_out;   // dead scratch until bn_transpose_out
    unsigned short* whi1  = (unsigned short*)sc;          // 294912 elems
    unsigned short* wlo1  = whi1 + 294912;
    unsigned short* whi2  = wlo1 + 294912;                // 36864 each below
    unsigned short* wlo2  = whi2 + 36864;
    unsigned short* whiD1 = wlo2 + 36864;
    unsigned short* wloD1 = whiD1 + 36864;
    unsigned short* whiD2 = wloD1 + 36864;
    unsigned short* wloD2 = whiD2 + 36864;
    unsigned short* whiD3 = wloD2 + 36864;
    unsigned short* wloD3 = whiD3 + 36864;
    float* imapF = (float*)(sc + 1769472);                // 1MB

    // 0. dtype detect + accum zero + weight pre-split
    detect_kernel<<<1, 64, 0, stream>>>((const unsigned*)cur_x, flag);
    zero_accum_kernel<<<1, 256, 0, stream>>>(accum);
    wsplit_kernel<128, 256><<<1152, 256, 0, stream>>>(up_w, whi1, wlo1, flag);
    wsplit_kernel<64, 64><<<144, 256, 0, stream>>>(conv2_w, whi2, wlo2, flag);
    wsplit_kernel<64, 64><<<144, 256, 0, stream>>>(d1_w, whiD1, wloD1, flag);
    wsplit_kernel<64, 64><<<144, 256, 0, stream>>>(d2_w, whiD2, wloD2, flag);
    wsplit_kernel<64, 64><<<144, 256, 0, stream>>>(d3_w, whiD3, wloD3, flag);

    // 1. u1 = conv3x3(dep_x; up) -> W0 NHWC [65536][256]
    conv3_mfma<128, 256, 64, 64, 4, true, false, false, false>
        <<<dim3(256, 4), 256, 0, stream>>>(dep_x, whi1, wlo1, up_b,
            nullptr, nullptr, nullptr, nullptr, nullptr, nullptr, W0, flag);
    // 2. stats(u1)
    stats_nhwc_kernel<256><<<256, 256, 0, stream>>>(W0, a0, 65536);
    // 3. imap
    imap_kernel<<<1024, 256, 0, stream>>>(in_map, imapF, flag);
    // 4. dep = shuffle(relu(bn(u1))) -> W1 NHWC [262144][64]
    shuffle_bn_nhwc_kernel<<<2048, 256, 0, stream>>>(W0, a0, up_g, up_be, W1, flag);
    // 5. t = dep + beta*conv3x3(cur_x * inc) -> W0 (inc computed inline)
    conv3_mfma<64, 64, 128, 128, 2, true, true, true, false>
        <<<dim3(1024, 1), 256, 0, stream>>>(cur_x, whi2, wlo2, conv2_b,
            imapF, W1, beta, nullptr, nullptr, nullptr, W0, flag);
    // 6. u_d1 = conv(t; d1) -> W1 ; stats
    conv3_mfma<64, 64, 128, 128, 2, false, false, false, false>
        <<<dim3(1024, 1), 256, 0, stream>>>(W0, whiD1, wloD1, d1_b,
            nullptr, nullptr, nullptr, nullptr, nullptr, nullptr, W1, flag);
    stats_nhwc_kernel<64><<<256, 256, 0, stream>>>(W1, a1, 262144);
    // 7. u_d2 = conv(relu(bn1(u_d1)); d2) -> W0 ; stats   (BN fused in staging)
    conv3_mfma<64, 64, 128, 128, 2, false, false, false, true>
        <<<dim3(1024, 1), 256, 0, stream>>>(W1, whiD2, wloD2, d2_b,
            nullptr, nullptr, nullptr, a1, d1_g, d1_be, W0, flag);
    stats_nhwc_kernel<64><<<256, 256, 0, stream>>>(W0, a2, 262144);
    // 8. u_d3 = conv(relu(bn2(u_d2)); d3) -> W1 ; stats
    conv3_mfma<64, 64, 128, 128, 2, false, false, false, true>
        <<<dim3(1024, 1), 256, 0, stream>>>(W0, whiD3, wloD3, d3_b,
            nullptr, nullptr, nullptr, a2, d2_g, d2_be, W1, flag);
    stats_nhwc_kernel<64><<<256, 256, 0, stream>>>(W1, a3, 262144);
    // 9. r3 = relu(bn3(u_d3)): NHWC->NCHW f32 (W0) + d_out dtype
    bn_transpose_out_kernel<<<4096, 256, 0, stream>>>(W1, a3, d3_g, d3_be,
                                                      W0, d_out, flag);
    // 10. output_map = conv7x7(r3) -> d_out + 16.7M
    conv7x7_kernel<<<dim3(8, 2, 16), 256, 0, stream>>>(W0, out_w, out_b, d_out, flag);
}